// Round 1
// baseline (2413.749 us; speedup 1.0000x reference)
//
#include <hip/hip_runtime.h>

typedef __attribute__((ext_vector_type(8))) short bf16x8;
typedef __attribute__((ext_vector_type(4))) float f32x4;

#define NBLK 256

typedef __attribute__((address_space(3))) unsigned lds_u;
typedef __attribute__((address_space(1))) const unsigned glb_u;

// ---------- helpers ----------
__device__ __forceinline__ unsigned short f2bf(float f) {
  unsigned u = __float_as_uint(f);
  unsigned r = u + 0x7fffu + ((u >> 16) & 1u);   // RNE
  return (unsigned short)(r >> 16);
}
__device__ __forceinline__ float bf2f(unsigned short h) {
  return __uint_as_float(((unsigned)h) << 16);
}
// packed = (hi_bits<<16) | lo_bits ; hi+lo reconstructs f to ~2^-16 rel
__device__ __forceinline__ unsigned pack_split(float f) {
  unsigned short hi = f2bf(f);
  float res = f - bf2f(hi);
  unsigned short lo = f2bf(res);
  return (((unsigned)hi) << 16) | (unsigned)lo;
}
// 8 packed elems (2x uint4) -> hi-frag / lo-frag (8 bf16 each)
__device__ __forceinline__ void unpack2(uint4 a0, uint4 a1, bf16x8& hi, bf16x8& lo) {
  union { bf16x8 v; unsigned u[4]; } H, L;
  H.u[0] = (a0.x >> 16) | (a0.y & 0xffff0000u);
  L.u[0] = (a0.x & 0xffffu) | (a0.y << 16);
  H.u[1] = (a0.z >> 16) | (a0.w & 0xffff0000u);
  L.u[1] = (a0.z & 0xffffu) | (a0.w << 16);
  H.u[2] = (a1.x >> 16) | (a1.y & 0xffff0000u);
  L.u[2] = (a1.x & 0xffffu) | (a1.y << 16);
  H.u[3] = (a1.z >> 16) | (a1.w & 0xffff0000u);
  L.u[3] = (a1.z & 0xffffu) | (a1.w << 16);
  hi = H.v; lo = L.v;
}
__device__ __forceinline__ float sigm(float x) { return 1.0f / (1.0f + __expf(-x)); }
__device__ __forceinline__ float tanh_f(float x) { return 1.0f - 2.0f / (__expf(2.0f * x) + 1.0f); }

// ---------- prep: pack weights into per-(WG,wave,layer,ktile) register-load layout ----------
// wreg[wg=256][wave=8][l=2][kt=8][lane=64][e=8] packed dwords.
// NEW K-mapping: every wave owns 128 K of W_hh (kt 0..3) THEN 128 K of W_ih (kt 4..7):
//   kloc = wv*128 + (kt&3)*32 + q*8 + e ;  kt<4 -> W_hh[col][kloc], else W_ih[col][kloc]
// (hs chunks first so they can be prefetched under the grid barrier.)
__global__ __launch_bounds__(256) void prep_kernel(
    const float* __restrict__ wih, const float* __restrict__ whh,
    const float* __restrict__ wfc_in, const float* __restrict__ hin,
    unsigned* __restrict__ wreg, unsigned* __restrict__ wfc, unsigned* __restrict__ xinit) {
  for (int e0 = 0; e0 < 8; ++e0) {
    unsigned idx = blockIdx.x * 2048u + (unsigned)e0 * 256u + threadIdx.x;
    if (idx < 16777216u) {
      unsigned wg   = idx >> 16;
      unsigned r    = idx & 65535u;
      unsigned wv   = r >> 13;
      unsigned r2   = r & 8191u;
      unsigned l    = r2 >> 12;
      unsigned r3   = r2 & 4095u;
      unsigned kt   = r3 >> 9;
      unsigned r4   = r3 & 511u;
      unsigned lane = r4 >> 3;
      unsigned e    = r4 & 7u;
      unsigned n = lane & 15u, q = lane >> 4;
      unsigned g = n >> 2, jj = n & 3u;
      unsigned col = (g << 10) + (wg << 2) + jj;
      unsigned kloc = (wv << 7) + ((kt & 3u) << 5) + (q << 3) + e;
      float v = (kt < 4u) ? whh[(l << 22) + (col << 10) + kloc]
                          : wih[(l << 22) + (col << 10) + kloc];
      wreg[idx] = pack_split(v);
    } else if (idx < 17825792u) {            // wfc [1024][1024]
      unsigned i2 = idx - 16777216u;
      wfc[i2] = pack_split(wfc_in[i2]);
    } else if (idx < 17891328u) {            // x_init packed
      unsigned i3 = idx - 17825792u;
      xinit[i3] = pack_split(hin[i3]);
    }
  }
}

// ---------- distributed grid barrier, FENCE-FREE ----------
// Layout: barp[(j)<<5] j=0..7 : 8 replicated generation words (one per 128B line)
//         barp[512+wid]       : per-block arrive flags
__device__ __forceinline__ void grid_barrier(unsigned* barp, unsigned g,
                                             int wid, int tid) {
  __syncthreads();
  if (wid == 0) {
    if (tid > 0 && tid < NBLK) {
      while (__hip_atomic_load(&barp[512 + tid], __ATOMIC_RELAXED,
                               __HIP_MEMORY_SCOPE_AGENT) < g) {
        __builtin_amdgcn_s_sleep(1);
      }
    }
    __syncthreads();
    if (tid < 8) {
      __hip_atomic_store(&barp[tid << 5], g, __ATOMIC_RELAXED, __HIP_MEMORY_SCOPE_AGENT);
    }
  } else {
    if (tid == 0) {
      __hip_atomic_store(&barp[512 + wid], g, __ATOMIC_RELAXED, __HIP_MEMORY_SCOPE_AGENT);
      while (__hip_atomic_load(&barp[(wid & 7) << 5], __ATOMIC_RELAXED,
                               __HIP_MEMORY_SCOPE_AGENT) < g) {
        __builtin_amdgcn_s_sleep(2);
      }
    }
  }
  __syncthreads();
}

// ---------- main persistent LSTM ----------
// Weights in regs; A staged via async global_load_lds (double-buffered, per-wave
// LDS region); h published to per-phase FRESH slabs via agent atomic stores.
// NEW: every wave's chunks 0-3 are the hs operand (published >=2 phases ago) and
// chunks 0,1 are issued DURING the grid barrier (after its first __syncthreads,
// so buf0's partials region is already consumed). Chunks 4-7 (xs, just-published)
// are issued post-barrier inside the kt pipeline. vmcnt(8) at iteration kt still
// guarantees chunk kt is complete (all-but-newest-8), independent of any early
// drains caused by the spin-loads' implicit vmcnt(0).
__global__ __launch_bounds__(512, 1) void lstm_main(
    const unsigned* __restrict__ wreg,
    unsigned* __restrict__ h0buf,      // [128][64][1024] (aliases wreg lower half)
    const unsigned* __restrict__ xinit,
    const unsigned* __restrict__ hzero,
    unsigned* __restrict__ rec,        // [128][64][1024] = h1 history
    const float* __restrict__ bih, const float* __restrict__ bhh,
    unsigned* __restrict__ barp) {
  __shared__ unsigned lds_stage[8 * 4096];  // 128 KB: per wave 16 KB (2 bufs x 8 KB)

  const int tid = threadIdx.x;
  const int wid = blockIdx.x;
  const int wave = tid >> 6;
  const int lane = tid & 63;
  const int q = lane >> 4;
  const int m16 = lane & 15;

  // ---- load this wave's weight slice into registers, then pin ----
  bf16x8 whi[2][8], wlo[2][8];
  {
    const unsigned* wb = wreg + ((size_t)wid << 16) + ((size_t)wave << 13) + (lane << 3);
    #pragma unroll
    for (int l = 0; l < 2; ++l)
      #pragma unroll
      for (int kt = 0; kt < 8; ++kt) {
        const unsigned* p = wb + (l << 12) + (kt << 9);
        uint4 a0 = *(const uint4*)p;
        uint4 a1 = *(const uint4*)(p + 4);
        unpack2(a0, a1, whi[l][kt], wlo[l][kt]);
      }
    #pragma unroll
    for (int l = 0; l < 2; ++l)
      #pragma unroll
      for (int kt = 0; kt < 8; ++kt) {
        asm volatile("" : "+v"(whi[l][kt]), "+v"(wlo[l][kt]));
      }
  }

  // EW thread state (threads 0..255 own (b=tid>>2, jj=tid&3))
  const int eb = tid >> 2;
  const int ej = tid & 3;
  float creg[2] = {0.0f, 0.0f};
  float biasr[2][4] = {{0, 0, 0, 0}, {0, 0, 0, 0}};
  if (tid < 256) {
    #pragma unroll
    for (int l = 0; l < 2; ++l)
      #pragma unroll
      for (int g = 0; g < 4; ++g) {
        int col = (g << 10) + (wid << 2) + ej;
        biasr[l][g] = bih[(l << 12) + col] + bhh[(l << 12) + col];
      }
  }

  // All blocks done reading wreg, then ONE-TIME acquire fence.
  grid_barrier(barp, 1u, wid, tid);
  __builtin_amdgcn_fence(__ATOMIC_ACQUIRE, "agent");

  const unsigned kb = (unsigned)(wave << 7);        // wave's 128-dword K-base (per operand)
  unsigned* const lds_w = lds_stage + (wave << 12); // this wave's 16 KB region
  const f32x4 fzero = {0.0f, 0.0f, 0.0f, 0.0f};

  // staging-issue lane geometry: instr i covers rows r=i*8+st_r, 16B slot st_cs
  const int st_r  = lane >> 3;
  const int st_cs = lane & 7;

  // chunk kt_: columns [kb + (kt_&3)*32, +32) of slab srcp_; XOR-swizzled slots
  #define ISSUE_CHUNK(kt_, bsel_, srcp_)                                           \
    {                                                                              \
      _Pragma("unroll")                                                            \
      for (int i = 0; i < 8; ++i) {                                                \
        int r = (i << 3) + st_r;                                                   \
        int c = st_cs ^ (r & 7);                                                   \
        const unsigned* gp = (srcp_) + (r << 10) + (((kt_) & 3) << 5) + (c << 2);  \
        unsigned* lp = lds_w + ((bsel_) << 11) + (i << 8);                         \
        __builtin_amdgcn_global_load_lds((glb_u*)gp, (lds_u*)lp, 16, 0, 0);        \
      }                                                                            \
    }

  // prefetch hs chunks 0,1 for phase (t=0,l=0): hs = hzero
  ISSUE_CHUNK(0, 0, hzero + kb)
  ISSUE_CHUNK(1, 1, hzero + kb)

  for (int t = 0; t < 128; ++t) {
    #pragma unroll
    for (int l = 0; l < 2; ++l) {
      const unsigned* xs;
      const unsigned* hsv;
      unsigned* dst;
      if (l == 0) {
        xs  = (t == 0) ? xinit : rec + ((t - 1) << 16);
        hsv = (t == 0) ? hzero : h0buf + ((t - 1) << 16);
        dst = h0buf + (t << 16);
      } else {
        xs  = h0buf + (t << 16);
        hsv = (t == 0) ? hzero : rec + ((t - 1) << 16);
        dst = rec + (t << 16);
      }
      const unsigned* srcx = xs + kb;
      const unsigned* srch = hsv + kb;

      f32x4 acc[4];
      #pragma unroll
      for (int mt = 0; mt < 4; ++mt) acc[mt] = fzero;

      // chunks 0,1 (hs) already in flight from the barrier-overlap prefetch
      #pragma unroll
      for (int kt = 0; kt < 8; ++kt) {
        const int bsel = kt & 1;
        if (kt < 7) {
          asm volatile("s_waitcnt vmcnt(8)" ::: "memory");
        } else {
          asm volatile("s_waitcnt vmcnt(0)" ::: "memory");
        }
        const unsigned* bufb = lds_w + (bsel << 11);
        bf16x8 ahi[4], alo[4];
        #pragma unroll
        for (int mt = 0; mt < 4; ++mt) {
          int row = (mt << 4) + m16;
          const unsigned* base = bufb + (row << 5);
          uint4 a0 = *(const uint4*)(base + ((((q << 1)    ) ^ (row & 7)) << 2));
          uint4 a1 = *(const uint4*)(base + ((((q << 1) | 1) ^ (row & 7)) << 2));
          unpack2(a0, a1, ahi[mt], alo[mt]);
        }
        asm volatile("s_waitcnt lgkmcnt(0)" ::: "memory");
        if (kt < 2) {
          ISSUE_CHUNK(kt + 2, bsel, srch)          // hs chunks 2,3
        } else if (kt < 6) {
          ISSUE_CHUNK(kt + 2, bsel, srcx)          // xs chunks 4..7 (post-barrier data)
        }
        #pragma unroll
        for (int mt = 0; mt < 4; ++mt) {
          acc[mt] = __builtin_amdgcn_mfma_f32_16x16x32_bf16(ahi[mt], whi[l][kt], acc[mt], 0, 0, 0);
          acc[mt] = __builtin_amdgcn_mfma_f32_16x16x32_bf16(ahi[mt], wlo[l][kt], acc[mt], 0, 0, 0);
          acc[mt] = __builtin_amdgcn_mfma_f32_16x16x32_bf16(alo[mt], whi[l][kt], acc[mt], 0, 0, 0);
        }
      }

      // partials -> this wave's own buf0 region (4352 B < 8 KB)
      {
        float* lds_pw = (float*)lds_w;
        #pragma unroll
        for (int mt = 0; mt < 4; ++mt)
          #pragma unroll
          for (int r = 0; r < 4; ++r) {
            int m = (mt << 4) + (q << 2) + r;
            lds_pw[m * 17 + m16] = acc[mt][r];
          }
      }
      __syncthreads();

      // reduce across 8 waves + elementwise; publish h via agent atomic store
      if (tid < 256) {
        float g4[4];
        #pragma unroll
        for (int g = 0; g < 4; ++g) {
          float s = biasr[l][g];
          #pragma unroll
          for (int w = 0; w < 8; ++w)
            s += ((const float*)(lds_stage + (w << 12)))[eb * 17 + (g << 2) + ej];
          g4[g] = s;
        }
        float ig = sigm(g4[0]);
        float fg = sigm(g4[1]);
        float gv = tanh_f(g4[2]);
        float og = sigm(g4[3]);
        float cn = fg * creg[l] + ig * gv;
        float hn = og * tanh_f(cn);
        creg[l] = cn;
        unsigned hp = pack_split(hn);
        int off = (eb << 10) + (wid << 2) + ej;
        __hip_atomic_store(&dst[off], hp, __ATOMIC_RELAXED, __HIP_MEMORY_SCOPE_AGENT);
      }

      // ---- grid barrier with hs-prefetch overlap for the NEXT phase ----
      __syncthreads();   // (A): partials consumed; publish stores drained (vmcnt)
      if (!(t == 127 && l == 1)) {
        // next phase: l==0 -> (t,1): hs' = (t==0)?hzero:rec[t-1]
        //             l==1 -> (t+1,0): hs' = h0buf[t]
        const unsigned* srch2 = ((l == 0)
            ? ((t == 0) ? hzero : rec + ((t - 1) << 16))
            : (h0buf + (t << 16))) + kb;
        ISSUE_CHUNK(0, 0, srch2)
        ISSUE_CHUNK(1, 1, srch2)
      }
      {
        const unsigned g = (unsigned)(2 * t + l + 2);
        if (wid == 0) {
          if (tid > 0 && tid < NBLK) {
            while (__hip_atomic_load(&barp[512 + tid], __ATOMIC_RELAXED,
                                     __HIP_MEMORY_SCOPE_AGENT) < g) {
              __builtin_amdgcn_s_sleep(1);
            }
          }
          __syncthreads();
          if (tid < 8) {
            __hip_atomic_store(&barp[tid << 5], g, __ATOMIC_RELAXED,
                               __HIP_MEMORY_SCOPE_AGENT);
          }
        } else {
          if (tid == 0) {
            __hip_atomic_store(&barp[512 + wid], g, __ATOMIC_RELAXED,
                               __HIP_MEMORY_SCOPE_AGENT);
            while (__hip_atomic_load(&barp[(wid & 7) << 5], __ATOMIC_RELAXED,
                                     __HIP_MEMORY_SCOPE_AGENT) < g) {
              __builtin_amdgcn_s_sleep(2);
            }
          }
        }
      }
      __syncthreads();   // (B): release; prefetched chunks 0,1 in flight
    }
  }
  #undef ISSUE_CHUNK
}

// ---------- FC: out[8192,1024] = rec @ Wfc^T + b_fc (split-bf16 MFMA) ----------
__global__ __launch_bounds__(256) void fc_kernel(
    const unsigned* __restrict__ rec, const unsigned* __restrict__ wfc,
    const float* __restrict__ bfc, float* __restrict__ out) {
  __shared__ unsigned a_lds[128 * 36];
  __shared__ unsigned w_lds[128 * 36];
  const int tid = threadIdx.x;
  const int wave = tid >> 6;
  const int lane = tid & 63;
  const int q = lane >> 4;
  const int m16 = lane & 15;
  const int m0 = (blockIdx.x >> 3) << 7;
  const int n0 = (blockIdx.x & 7) << 7;
  const f32x4 fzero = {0.0f, 0.0f, 0.0f, 0.0f};

  f32x4 acc[2][8];
  for (int mt = 0; mt < 2; ++mt)
    for (int nt = 0; nt < 8; ++nt) acc[mt][nt] = fzero;

  for (int kc = 0; kc < 32; ++kc) {
    __syncthreads();
    #pragma unroll
    for (int i = 0; i < 4; ++i) {
      int c = (i << 8) + tid;
      int r = c >> 3;
      int cc = (c & 7) << 2;
      *(uint4*)(a_lds + r * 36 + cc) = *(const uint4*)(rec + ((m0 + r) << 10) + (kc << 5) + cc);
      *(uint4*)(w_lds + r * 36 + cc) = *(const uint4*)(wfc + ((n0 + r) << 10) + (kc << 5) + cc);
    }
    __syncthreads();

    bf16x8 ahi[2], alo[2];
    #pragma unroll
    for (int mt = 0; mt < 2; ++mt) {
      int arow = (wave << 5) + (mt << 4) + m16;
      uint4 a0 = *(const uint4*)(a_lds + arow * 36 + (q << 3));
      uint4 a1 = *(const uint4*)(a_lds + arow * 36 + (q << 3) + 4);
      unpack2(a0, a1, ahi[mt], alo[mt]);
    }
    #pragma unroll
    for (int nt = 0; nt < 8; ++nt) {
      int wrow = (nt << 4) + m16;
      uint4 b0 = *(const uint4*)(w_lds + wrow * 36 + (q << 3));
      uint4 b1 = *(const uint4*)(w_lds + wrow * 36 + (q << 3) + 4);
      bf16x8 bhi, blo;
      unpack2(b0, b1, bhi, blo);
      #pragma unroll
      for (int mt = 0; mt < 2; ++mt) {
        acc[mt][nt] = __builtin_amdgcn_mfma_f32_16x16x32_bf16(ahi[mt], bhi, acc[mt][nt], 0, 0, 0);
        acc[mt][nt] = __builtin_amdgcn_mfma_f32_16x16x32_bf16(ahi[mt], blo, acc[mt][nt], 0, 0, 0);
        acc[mt][nt] = __builtin_amdgcn_mfma_f32_16x16x32_bf16(alo[mt], bhi, acc[mt][nt], 0, 0, 0);
      }
    }
  }
  #pragma unroll
  for (int mt = 0; mt < 2; ++mt)
    #pragma unroll
    for (int nt = 0; nt < 8; ++nt) {
      int n = n0 + (nt << 4) + m16;
      float bv = bfc[n];
      #pragma unroll
      for (int r2 = 0; r2 < 4; ++r2) {
        int m = m0 + (wave << 5) + (mt << 4) + (q << 2) + r2;
        out[(m << 10) + n] = acc[mt][nt][r2] + bv;
      }
    }
}

// ---------- launch ----------
extern "C" void kernel_launch(void* const* d_in, const int* in_sizes, int n_in,
                              void* d_out, int out_size, void* d_ws, size_t ws_size,
                              hipStream_t stream) {
  const float* h_in = (const float*)d_in[0];
  const float* W_ih = (const float*)d_in[1];
  const float* W_hh = (const float*)d_in[2];
  const float* b_ih = (const float*)d_in[3];
  const float* b_hh = (const float*)d_in[4];
  const float* W_fc = (const float*)d_in[5];
  const float* b_fc = (const float*)d_in[6];
  (void)in_sizes; (void)n_in; (void)out_size; (void)ws_size;

  char* ws = (char*)d_ws;
  unsigned* wreg  = (unsigned*)(ws + 0);          // 64 MB: [256][8][2][8][64][8]
  unsigned* h0buf = (unsigned*)(ws + 0);          // 32 MB, ALIASES wreg lower half
  unsigned* wfc   = (unsigned*)(ws + 67108864);   // 4 MB
  unsigned* xinit = (unsigned*)(ws + 71303168);   // 256 KB (packed x_init)
  unsigned* hzero = (unsigned*)(ws + 71565312);   // 256 KB, stays zero
  unsigned* barp  = (unsigned*)(ws + 71827456);   // 4 KB: [j<<5]=gen copies, [512+wid]=flags
  unsigned* rec   = (unsigned*)(ws + 72616192);   // 32 MB: [128][64][1024] = h1 history
  float*    out   = (float*)d_out;

  // zero: hzero + barp (contiguous)
  (void)hipMemsetAsync(ws + 71565312, 0, 262144 + 266240, stream);

  prep_kernel<<<dim3(8736), dim3(256), 0, stream>>>(W_ih, W_hh, W_fc, h_in,
                                                    wreg, wfc, xinit);

  lstm_main<<<dim3(NBLK), dim3(512), 0, stream>>>(wreg, h0buf, xinit, hzero, rec,
                                                  b_ih, b_hh, barp);

  fc_kernel<<<dim3(512), dim3(256), 0, stream>>>(rec, wfc, b_fc, out);
}